// Round 1
// baseline (793.257 us; speedup 1.0000x reference)
//
#include <hip/hip_runtime.h>

#define NU 10000
#define NREV_DST 8000
#define MAIN_BLOCKS 2500   // 2500 blocks x 4 waves = 10000 users, one user per wave

// ws float layout (unchanged):
//   [0)      Bstate[8*128]   = 1024
//   [1024)   delta_acc[512]
//   [1536)   Wbuf[64*8]      = 512   (TRANSPOSED: W[n][k] at n*8+k)
//   [2048)   allu[NU*16*64]

__device__ __forceinline__ float rlane(float v, int l) {
    return __int_as_float(__builtin_amdgcn_readlane(__float_as_int(v), l));
}

template <int N, int K>
__global__ __launch_bounds__(256, 4) void main_iter(
    const float* __restrict__ emb, const int* __restrict__ idx,
    const float* __restrict__ Sg, const float* __restrict__ Wg,
    float* __restrict__ delta_acc, float* __restrict__ allu,
    int slot0, int write_high, int write_delta)
{
    // S stored XOR-swizzled: S[r][c] at r*64 + (((c>>2)^(r&15))<<2 | (c&3)).
    // Conflict-free for b32 column reads (phase B) AND b128 own-row reads (phase C).
    __shared__ float s_S[64 * 64];
    // per-wave slab: 64 rows x 16-wide e-slice (time-multiplexed), stride 20 floats
    __shared__ float s_embT[4][64 * 20];

    const int tid  = threadIdx.x;
    const int w    = tid >> 6;
    const int lane = tid & 63;

    for (int i = tid; i < 64 * 64; i += 256) {
        const int r = i >> 6, c = i & 63;
        s_S[r * 64 + ((((c >> 2) ^ (r & 15)) << 2) | (c & 3))] = Sg[i];
    }
    __syncthreads();

    // wave-uniform user id -> idx loads become s_load
    const int u = __builtin_amdgcn_readfirstlane((int)blockIdx.x * 4 + w);
    const int* uidx = idx + u * N;

    // ---- phase A: g[k][e=lane] = sum_n W[n][k] * emb[idx[n]][lane]
    // rows are wave-uniform -> coalesced 256B broadcast-row loads, NO LDS.
    float g[K];
#pragma unroll
    for (int k = 0; k < K; ++k) g[k] = 0.f;
#pragma unroll
    for (int r0 = 0; r0 < N; r0 += 8) {
        float ev[8];
#pragma unroll
        for (int i = 0; i < 8; ++i)
            if (r0 + i < N) {
                const int row = uidx[r0 + i];          // s_load (uniform)
                ev[i] = emb[(size_t)row * 64 + lane];  // coalesced row
            }
#pragma unroll
        for (int i = 0; i < 8; ++i)
            if (r0 + i < N) {
#pragma unroll
                for (int k = 0; k < K; ++k)
                    g[k] = fmaf(Wg[(r0 + i) * 8 + k], ev[i], g[k]);  // W via s_load
            }
    }

    // ---- phase B: raw[k][d=lane] = sum_e g[k][e] * S[e][d]
    // g broadcast via v_readlane (VALU), S column via conflict-free b32.
    float raw[K];
#pragma unroll
    for (int k = 0; k < K; ++k) raw[k] = 0.f;
    {
        const int l4 = lane >> 2, lo = lane & 3;
#pragma unroll 4
        for (int eo = 0; eo < 16; ++eo) {
            const int a = eo * 64 + (((l4 ^ eo) << 2) | lo);
            const float sv0 = s_S[a];
            const float sv1 = s_S[a + 16 * 64];
            const float sv2 = s_S[a + 32 * 64];
            const float sv3 = s_S[a + 48 * 64];
#pragma unroll
            for (int k = 0; k < K; ++k) {
                raw[k] = fmaf(rlane(g[k], eo),      sv0, raw[k]);
                raw[k] = fmaf(rlane(g[k], eo + 16), sv1, raw[k]);
                raw[k] = fmaf(rlane(g[k], eo + 32), sv2, raw[k]);
                raw[k] = fmaf(rlane(g[k], eo + 48), sv3, raw[k]);
            }
        }
    }

    // ---- squash (same expression/order as before for matching numerics)
    float sq = 0.f;
#pragma unroll
    for (int k = 0; k < K; ++k) sq = fmaf(raw[k], raw[k], sq);
    const float f = (sq / (1.0f + sq)) / sqrtf(sq + 1e-9f);
    float hi[K];
#pragma unroll
    for (int k = 0; k < K; ++k) hi[k] = f * raw[k];

    if (write_high) {
#pragma unroll
        for (int k = 0; k < K; ++k)
            allu[(size_t)u * 1024 + (slot0 + k) * 64 + lane] = hi[k];
    }

    if (write_delta) {
        // ---- phase C: hs[k][e=lane] = sum_d hi[k][d] * S[lane][d]
        // own-row b128 reads of swizzled s_S + readlane broadcast of hi.
        float hs[K];
#pragma unroll
        for (int k = 0; k < K; ++k) hs[k] = 0.f;
        {
            const int rowbase = lane * 64, l15 = lane & 15;
#pragma unroll 4
            for (int d4 = 0; d4 < 16; ++d4) {
                const float4 sv = *(const float4*)&s_S[rowbase + ((d4 ^ l15) << 2)];
#pragma unroll
                for (int k = 0; k < K; ++k) {
                    hs[k] = fmaf(rlane(hi[k], d4 * 4 + 0), sv.x, hs[k]);
                    hs[k] = fmaf(rlane(hi[k], d4 * 4 + 1), sv.y, hs[k]);
                    hs[k] = fmaf(rlane(hi[k], d4 * 4 + 2), sv.z, hs[k]);
                    hs[k] = fmaf(rlane(hi[k], d4 * 4 + 3), sv.w, hs[k]);
                }
            }
        }

        // ---- phase D: delta[k][n=lane] = sum_e emb[idx[n]][e] * hs[k][e]
        // e-chunked: stage a 16-wide column slice of all N rows, read own row b128.
        float dreg[K];
#pragma unroll
        for (int k = 0; k < K; ++k) dreg[k] = 0.f;

        constexpr int RP = (N + 15) / 16;
        const int rr = lane >> 2, jj = lane & 3;
        int rows[RP];
#pragma unroll
        for (int p = 0; p < RP; ++p) {
            const int r = p * 16 + rr;
            rows[p] = (N % 16 == 0 || r < N) ? uidx[r] : 0;
        }

        for (int ec = 0; ec < 4; ++ec) {
            const int e0 = ec * 16;
#pragma unroll
            for (int p = 0; p < RP; ++p) {
                const int r = p * 16 + rr;
                if (N % 16 == 0 || r < N) {
                    const float4 v =
                        *(const float4*)(emb + (size_t)rows[p] * 64 + e0 + jj * 4);
                    *(float4*)&s_embT[w][r * 20 + jj * 4] = v;  // wave-private slab
                }
            }
#pragma unroll
            for (int e4 = 0; e4 < 4; ++e4) {
                const float4 v = *(const float4*)&s_embT[w][lane * 20 + e4 * 4];
                const int e = e0 + e4 * 4;
#pragma unroll
                for (int k = 0; k < K; ++k) {
                    dreg[k] = fmaf(v.x, rlane(hs[k], e + 0), dreg[k]);
                    dreg[k] = fmaf(v.y, rlane(hs[k], e + 1), dreg[k]);
                    dreg[k] = fmaf(v.z, rlane(hs[k], e + 2), dreg[k]);
                    dreg[k] = fmaf(v.w, rlane(hs[k], e + 3), dreg[k]);
                }
            }
        }

        // cross-wave reduce (reuse slabs), one atomic per (k,n) per block
#pragma unroll
        for (int k = 0; k < K; ++k) s_embT[w][k * 64 + lane] = dreg[k];
        __syncthreads();
        for (int t = tid; t < K * 64; t += 256) {
            const float s = s_embT[0][t] + s_embT[1][t] + s_embT[2][t] + s_embT[3][t];
            if ((t & 63) < N) atomicAdd(&delta_acc[t], s);  // lanes>=N hold garbage -> masked
        }
    }
}

// Apply delta -> B, zero delta, compute next softmax W (transposed layout n*8+k).
__global__ __launch_bounds__(1024) void update_kernel(
    float* __restrict__ Bstate, float* __restrict__ delta_acc,
    const float* __restrict__ Bin, float* __restrict__ Wout,
    int init, int Kc, int nc, int Kn, int nn)
{
    __shared__ float sB[1024];
    const int t = threadIdx.x;
    float b = init ? Bin[t] : Bstate[t];
    const int k = t >> 7, n = t & 127;
    float d = 0.f;
    if (!init && k < Kc && n < nc) d = delta_acc[k * 64 + n];
    __syncthreads();
    if (t < 512) delta_acc[t] = 0.f;  // fresh accumulator for next main launch
    b += d;
    Bstate[t] = b;
    sB[t] = b;
    __syncthreads();
    const int wv = t >> 6, lane = t & 63;
    if (wv < Kn) {
        float v = (lane < nn) ? sB[wv * 128 + lane] : -3.4e38f;
        float m = v;
#pragma unroll
        for (int off = 32; off >= 1; off >>= 1) m = fmaxf(m, __shfl_xor(m, off, 64));
        const float e = (lane < nn) ? expf(v - m) : 0.f;
        float s = e;
#pragma unroll
        for (int off = 32; off >= 1; off >>= 1) s += __shfl_xor(s, off, 64);
        Wout[lane * 8 + wv] = e / s;  // transposed: W[n][k]
    }
}

__global__ __launch_bounds__(256) void attn_kernel(
    const float* __restrict__ allu, const float* __restrict__ M1g,
    const float* __restrict__ M2g, float* __restrict__ out)
{
    __shared__ float sM1[64 * 65];
    __shared__ float sU[4][16 * 64];
    const int tid = threadIdx.x, w = tid >> 6, lane = tid & 63;
    for (int i = tid; i < 4096; i += 256)
        sM1[(i >> 6) * 65 + (i & 63)] = M1g[i];
    __syncthreads();
    const int u = blockIdx.x * 4 + w;
    if (u >= NU) return;
    for (int i = 0; i < 16; ++i)
        sU[w][i * 64 + lane] = allu[(size_t)u * 1024 + i * 64 + lane];
    const float m2 = M2g[lane];
    float acc[16];
#pragma unroll
    for (int i = 0; i < 16; ++i) acc[i] = 0.f;
    for (int d = 0; d < 64; ++d) {
        const float m1v = sM1[d * 65 + lane];
#pragma unroll
        for (int i = 0; i < 16; ++i) acc[i] = fmaf(sU[w][i * 64 + d], m1v, acc[i]);
    }
    float s2[16];
#pragma unroll
    for (int i = 0; i < 16; ++i) {
        float c = tanhf(acc[i]) * m2;
#pragma unroll
        for (int off = 32; off >= 1; off >>= 1) c += __shfl_xor(c, off, 64);
        s2[i] = c * c;
    }
    float mx = 0.f;  // 8 padded slots have s=0
#pragma unroll
    for (int i = 0; i < 16; ++i) mx = fmaxf(mx, s2[i]);
    float den = 8.f * expf(-mx);
    float att[16];
#pragma unroll
    for (int i = 0; i < 16; ++i) { att[i] = expf(s2[i] - mx); den += att[i]; }
    const float inv = 1.0f / den;
    float o = 0.f;
#pragma unroll
    for (int i = 0; i < 16; ++i) o = fmaf(att[i] * inv, sU[w][i * 64 + lane], o);
    out[(size_t)u * 64 + lane] = o;
}

__global__ __launch_bounds__(256) void review_kernel(
    const float* __restrict__ tag, const int* __restrict__ idx, float* __restrict__ out)
{
    const int tid = threadIdx.x, w = tid >> 6, lane = tid & 63;
    const int r = blockIdx.x * 4 + w;
    if (r >= NREV_DST) return;
    float acc = 0.f;
    for (int j = 0; j < 20; ++j) {
        const int t = idx[r * 20 + j];
        acc += tag[(size_t)t * 64 + lane];
    }
    out[(size_t)r * 64 + lane] = acc / 20.0f;
}

extern "C" void kernel_launch(void* const* d_in, const int* in_sizes, int n_in,
                              void* d_out, int out_size, void* d_ws, size_t ws_size,
                              hipStream_t stream)
{
    const float* review_embed = (const float*)d_in[0];
    const float* tag_embed    = (const float*)d_in[1];
    const int*   idx_urt      = (const int*)d_in[2];
    const int*   idx_uqt      = (const int*)d_in[3];
    const int*   idx_uprt     = (const int*)d_in[4];
    const int*   idx_rht      = (const int*)d_in[5];
    const float* B_in         = (const float*)d_in[6];
    const float* S_g          = (const float*)d_in[7];
    const float* M1           = (const float*)d_in[8];
    const float* M2           = (const float*)d_in[9];

    float* ws     = (float*)d_ws;
    float* Bstate = ws;
    float* delta  = ws + 1024;
    float* Wbuf   = ws + 1536;
    float* allu   = ws + 2048;
    float* out    = (float*)d_out;

    const dim3 mg(MAIN_BLOCKS), mb(256);
    const dim3 one(1), ub(1024);

    // init: copy B, zero delta, W for call1 (K=6, n=64)
    hipLaunchKernelGGL(update_kernel, one, ub, 0, stream,
                       Bstate, delta, B_in, Wbuf, 1, 0, 0, 6, 64);

    // call 1: review_embed[idx_urt], n=64, K=6, slots 0..5
    for (int itr = 0; itr < 3; ++itr) {
        hipLaunchKernelGGL((main_iter<64, 6>), mg, mb, 0, stream,
                           review_embed, idx_urt, S_g, Wbuf, delta, allu,
                           0, (itr == 2) ? 1 : 0, 1);
        const int Kn = (itr == 2) ? 5 : 6;
        const int nn = (itr == 2) ? 32 : 64;
        hipLaunchKernelGGL(update_kernel, one, ub, 0, stream,
                           Bstate, delta, B_in, Wbuf, 0, 6, 64, Kn, nn);
    }
    // call 2: tag_embed[idx_uqt], n=32, K=5, slots 6..10
    for (int itr = 0; itr < 3; ++itr) {
        hipLaunchKernelGGL((main_iter<32, 5>), mg, mb, 0, stream,
                           tag_embed, idx_uqt, S_g, Wbuf, delta, allu,
                           6, (itr == 2) ? 1 : 0, 1);
        const int nn = (itr == 2) ? 50 : 32;
        hipLaunchKernelGGL(update_kernel, one, ub, 0, stream,
                           Bstate, delta, B_in, Wbuf, 0, 5, 32, 5, nn);
    }
    // call 3: review_embed[idx_uprt], n=50, K=5, slots 11..15
    for (int itr = 0; itr < 3; ++itr) {
        const int last = (itr == 2);
        hipLaunchKernelGGL((main_iter<50, 5>), mg, mb, 0, stream,
                           review_embed, idx_uprt, S_g, Wbuf, delta, allu,
                           11, last, last ? 0 : 1);
        if (!last)
            hipLaunchKernelGGL(update_kernel, one, ub, 0, stream,
                               Bstate, delta, B_in, Wbuf, 0, 5, 50, 5, 50);
    }

    hipLaunchKernelGGL(attn_kernel, dim3((NU + 3) / 4), mb, 0, stream, allu, M1, M2, out);
    hipLaunchKernelGGL(review_kernel, dim3((NREV_DST + 3) / 4), mb, 0, stream,
                       tag_embed, idx_rht, out + (size_t)NU * 64);
}